// Round 6
// baseline (105.095 us; speedup 1.0000x reference)
//
#include <hip/hip_runtime.h>

#define F 16
#define XL 128

// bands layout in d_ws: float bands[2][5][128]
//   pass 0 = row operator (x/w direction), pass 1 = column operator (y/h)
//   bands[p][d][pos] = coefficient of u[pos + d - 2] in deviation at pos.
//   Out-of-range taps stored as 0 (so garbage neighbors are annihilated).

__device__ __forceinline__ float g1f(const float* __restrict__ w1,
                                     const float* __restrict__ w1L,
                                     const float* __restrict__ w1R,
                                     int f, int v, int wp) {
  if (v == 0) {
    if (wp == 0) return w1L[f * 2 + 0];
    if (wp == 1) return w1L[f * 2 + 1];
    return 0.f;
  }
  if (v == XL - 1) {
    if (wp == XL - 2) return w1R[f * 2 + 0];
    if (wp == XL - 1) return w1R[f * 2 + 1];
    return 0.f;
  }
  int k = wp - (v - 1);
  return (k >= 0 && k < 3) ? w1[f * 3 + k] : 0.f;
}

__global__ __launch_bounds__(256)
void build_bands_kernel(const float* __restrict__ wX1, const float* __restrict__ wX1L,
                        const float* __restrict__ wX1R, const float* __restrict__ wY1,
                        const float* __restrict__ wY1L, const float* __restrict__ wY1R,
                        const float* __restrict__ wX2, const float* __restrict__ wX2L,
                        const float* __restrict__ wX2R, const float* __restrict__ wY2,
                        const float* __restrict__ wY2L, const float* __restrict__ wY2R,
                        const float* __restrict__ wfc, float* __restrict__ bands) {
  __shared__ float r1s[2][3], r1Ls[2][2], r1Rs[2][2];
  __shared__ float qs[2][F][3], qLs[2][F][2], qRs[2][F][2];

  const int t = threadIdx.x;
  if (t < 6) {
    int p = t / 3, k = t % 3;
    const float* w1 = p ? wY1 : wX1;
    int off = p ? F : 0;
    float s = 0.f;
    for (int f = 0; f < F; ++f) s += wfc[off + f] * w1[f * 3 + k];
    r1s[p][k] = s;
  } else if (t < 10) {
    int t2 = t - 6; int p = t2 / 2, k = t2 % 2;
    const float* w1L = p ? wY1L : wX1L;
    int off = p ? F : 0;
    float s = 0.f;
    for (int f = 0; f < F; ++f) s += wfc[off + f] * w1L[f * 2 + k];
    r1Ls[p][k] = s;
  } else if (t < 14) {
    int t2 = t - 10; int p = t2 / 2, k = t2 % 2;
    const float* w1R = p ? wY1R : wX1R;
    int off = p ? F : 0;
    float s = 0.f;
    for (int f = 0; f < F; ++f) s += wfc[off + f] * w1R[f * 2 + k];
    r1Rs[p][k] = s;
  } else if (t < 14 + 96) {
    int t2 = t - 14; int p = t2 / 48; int r = t2 % 48; int fi = r / 3, k = r % 3;
    const float* w2 = p ? wY2 : wX2;
    int off = p ? 3 * F : 2 * F;
    float s = 0.f;
    for (int fo = 0; fo < F; ++fo) s += wfc[off + fo] * w2[(fo * F + fi) * 3 + k];
    qs[p][fi][k] = s;
  } else if (t < 110 + 64) {
    int t2 = t - 110; int p = t2 / 32; int r = t2 % 32; int fi = r / 2, k = r % 2;
    const float* w2L = p ? wY2L : wX2L;
    int off = p ? 3 * F : 2 * F;
    float s = 0.f;
    for (int fo = 0; fo < F; ++fo) s += wfc[off + fo] * w2L[(fo * F + fi) * 2 + k];
    qLs[p][fi][k] = s;
  } else if (t < 174 + 64) {
    int t2 = t - 174; int p = t2 / 32; int r = t2 % 32; int fi = r / 2, k = r % 2;
    const float* w2R = p ? wY2R : wX2R;
    int off = p ? 3 * F : 2 * F;
    float s = 0.f;
    for (int fo = 0; fo < F; ++fo) s += wfc[off + fo] * w2R[(fo * F + fi) * 2 + k];
    qRs[p][fi][k] = s;
  }
  __syncthreads();

  int gid = blockIdx.x * 256 + t;
  if (gid >= 2 * XL * 5) return;
  const int p = gid / (XL * 5);
  const int rem = gid % (XL * 5);
  const int w = rem / 5;
  const int d = rem % 5;
  const int wp = w + d - 2;

  const float* w1  = p ? wY1  : wX1;
  const float* w1L = p ? wY1L : wX1L;
  const float* w1R = p ? wY1R : wX1R;

  float c = 0.f;
  if (wp >= 0 && wp < XL) {
    if (w == 0) {
      if (wp == 0)       c += r1Ls[p][0];
      else if (wp == 1)  c += r1Ls[p][1];
    } else if (w == XL - 1) {
      if (wp == XL - 2)      c += r1Rs[p][0];
      else if (wp == XL - 1) c += r1Rs[p][1];
    } else {
      int k = wp - (w - 1);
      if (k >= 0 && k < 3) c += r1s[p][k];
    }
    if (w == 0) {
      for (int vi = 0; vi < 2; ++vi)
        for (int fi = 0; fi < F; ++fi)
          c += qLs[p][fi][vi] * g1f(w1, w1L, w1R, fi, vi, wp);
    } else if (w == XL - 1) {
      for (int vi = 0; vi < 2; ++vi)
        for (int fi = 0; fi < F; ++fi)
          c += qRs[p][fi][vi] * g1f(w1, w1L, w1R, fi, XL - 2 + vi, wp);
    } else {
      for (int k2 = 0; k2 < 3; ++k2) {
        int v = w - 1 + k2;
        for (int fi = 0; fi < F; ++fi)
          c += qs[p][fi][k2] * g1f(w1, w1L, w1R, fi, v, wp);
      }
    }
  }
  bands[(p * 5 + d) * XL + w] = c;
}

// DPP whole-wave lane shifts (VALU pipe, no LDS). shr1: lane i <- lane i-1
// (lane 0 gets 0); shl1: lane i <- lane i+1 (lane 63 gets 0).
__device__ __forceinline__ float dpp_shr1(float x) {
  return __int_as_float(
      __builtin_amdgcn_update_dpp(0, __float_as_int(x), 0x138, 0xf, 0xf, true));
}
__device__ __forceinline__ float dpp_shl1(float x) {
  return __int_as_float(
      __builtin_amdgcn_update_dpp(0, __float_as_int(x), 0x130, 0xf, 0xf, true));
}

// Register-resident trapezoidal stencil, v2 (more TLP, conflict-free halos).
// 256 blocks = 64 images x 4 col-slabs (64-col buffer = 32 interior +
// 16-col halo each side). 512 threads = 8 waves x 8 cols (2 waves/SIMD,
// 1 block/CU). Lane z owns rows 2z,2z+1 x 8 cols in registers; a wave spans
// all 128 rows, so all vertical taps come from lane+-1 via DPP. Horizontal
// group-edge taps are exchanged as ONE float4 per lane per side
// (ds_*_b128, 16 B/lane contiguous -> conflict-free), double-buffered.
__global__ __launch_bounds__(512)
void fd_reg_kernel(const float* __restrict__ x_in, const float* __restrict__ bands,
                   const int* __restrict__ fdp, float* __restrict__ x_out) {
  __shared__ float4 hbuf[2][8][2][64];   // [buf][group][side L/R][lane] = 32 KB

  const int tid = threadIdx.x;
  const int z = tid & 63;        // lane -> row pair
  const int w = tid >> 6;        // wave -> 8-col group (wave-uniform)
  const int n = blockIdx.x >> 2;
  const int s = blockIdx.x & 3;
  int cs0 = 32 * s - 16; if (cs0 < 0) cs0 = 0; if (cs0 > 64) cs0 = 64;
  const int c0 = cs0 + 8 * w;    // first col owned by this thread
  const int r0 = 2 * z, r1 = 2 * z + 1;

  const float* img = x_in + n * XL * XL;

  // field registers: f0 = row r0, f1 = row r1, 8 cols each
  float f0[8], f1[8];
  {
    const float4* a = (const float4*)(img + r0 * XL + c0);
    const float4* b = (const float4*)(img + r1 * XL + c0);
#pragma unroll
    for (int m = 0; m < 2; ++m) {
      const float4 v = a[m];
      f0[4 * m] = v.x; f0[4 * m + 1] = v.y; f0[4 * m + 2] = v.z; f0[4 * m + 3] = v.w;
      const float4 u = b[m];
      f1[4 * m] = u.x; f1[4 * m + 1] = u.y; f1[4 * m + 2] = u.z; f1[4 * m + 3] = u.w;
    }
  }

  // coefficients. Cols k=2..5 are always interior (image cols 0,1,126,127
  // can only be k=0,1,6,7); rows vary only at z=0,63 -> per-lane load.
  float rbi[5], rbe0[5], rbe1[5], rbe6[5], rbe7[5], cb0[5], cb1[5];
#pragma unroll
  for (int d = 0; d < 5; ++d) {
    rbi[d]  = bands[d * XL + 64];
    rbe0[d] = bands[d * XL + c0];
    rbe1[d] = bands[d * XL + c0 + 1];
    rbe6[d] = bands[d * XL + c0 + 6];
    rbe7[d] = bands[d * XL + c0 + 7];
    cb0[d]  = bands[(5 + d) * XL + r0];
    cb1[d]  = bands[(5 + d) * XL + r1];
  }

  const int fdb = fdp[0];
  const int wl = (w > 0) ? w - 1 : 0;   // clamped: garbage-but-finite at slab edge;
  const int wr = (w < 7) ? w + 1 : 7;   // corruption advances 2 cols/iter < 16-col margin

  for (int t = 0; t < fdb; ++t) {
    const int b = t & 1;
    // publish group-edge pairs: one float4 per lane per side, lane-contiguous
    hbuf[b][w][0][z] = make_float4(f0[0], f0[1], f1[0], f1[1]);   // left edge
    hbuf[b][w][1][z] = make_float4(f0[6], f0[7], f1[6], f1[7]);   // right edge
    __syncthreads();
    const float4 lh = hbuf[b][wl][1][z];  // cols c0-2,c0-1 (rows r0: x,y; r1: z,w)
    const float4 rh = hbuf[b][wr][0][z];  // cols c0+8,c0+9

    float om1_0 = 0.f, om1_1 = 0.f;       // old f[k-1] (k>=2 path)
#pragma unroll
    for (int k = 0; k < 8; ++k) {
      const float o0 = f0[k], o1 = f1[k];
      // vertical taps via DPP: rows r0-2, r0-1 (=r1-2), r1+1, r1+2
      const float vm2 = dpp_shr1(o0);   // lane z-1 row0 = row 2z-2
      const float vm1 = dpp_shr1(o1);   // lane z-1 row1 = row 2z-1
      const float vp2 = dpp_shl1(o0);   // lane z+1 row0 = row 2z+2
      const float vp3 = dpp_shl1(o1);   // lane z+1 row1 = row 2z+3
      // horizontal taps (old values; compile-time selects under unroll)
      const float hm2_0 = (k == 0) ? lh.x : (k == 1) ? lh.y : f0[k - 2] * 0.f + om1_0 * 0.f + __builtin_huge_valf() * 0.f + ((k >= 2) ? 0.f : 0.f);
      // (the line above is replaced just below — see note)
      const float hm2_0r = (k == 0) ? lh.x : (k == 1) ? lh.y : 0.f;
      (void)hm2_0; (void)hm2_0r;
      float hm2a_0, hm1a_0, hm2a_1, hm1a_1;
      if (k == 0)      { hm2a_0 = lh.x; hm1a_0 = lh.y; hm2a_1 = lh.z; hm1a_1 = lh.w; }
      else if (k == 1) { hm2a_0 = lh.y; hm1a_0 = om1_0; hm2a_1 = lh.w; hm1a_1 = om1_1; }
      else             { hm2a_0 = f0[k - 2]; hm1a_0 = om1_0; hm2a_1 = f1[k - 2]; hm1a_1 = om1_1; }
      const float hp1_0 = (k < 7) ? f0[k + 1] : rh.x;
      const float hp2_0 = (k < 6) ? f0[k + 2] : ((k == 6) ? rh.x : rh.y);
      const float hp1_1 = (k < 7) ? f1[k + 1] : rh.z;
      const float hp2_1 = (k < 6) ? f1[k + 2] : ((k == 6) ? rh.z : rh.w);
      // row-band coeffs for this col (compile-time select under unroll)
      float c0b, c1b, c2b, c3b, c4b;
      if (k == 0)      { c0b = rbe0[0]; c1b = rbe0[1]; c2b = rbe0[2]; c3b = rbe0[3]; c4b = rbe0[4]; }
      else if (k == 1) { c0b = rbe1[0]; c1b = rbe1[1]; c2b = rbe1[2]; c3b = rbe1[3]; c4b = rbe1[4]; }
      else if (k == 6) { c0b = rbe6[0]; c1b = rbe6[1]; c2b = rbe6[2]; c3b = rbe6[3]; c4b = rbe6[4]; }
      else if (k == 7) { c0b = rbe7[0]; c1b = rbe7[1]; c2b = rbe7[2]; c3b = rbe7[3]; c4b = rbe7[4]; }
      else             { c0b = rbi[0];  c1b = rbi[1];  c2b = rbi[2];  c3b = rbi[3];  c4b = rbi[4];  }

      const float n0 = o0
        + c0b * hm2a_0 + c1b * hm1a_0 + c2b * o0 + c3b * hp1_0 + c4b * hp2_0
        + cb0[0] * vm2 + cb0[1] * vm1 + cb0[2] * o0 + cb0[3] * o1 + cb0[4] * vp2;
      const float n1 = o1
        + c0b * hm2a_1 + c1b * hm1a_1 + c2b * o1 + c3b * hp1_1 + c4b * hp2_1
        + cb1[0] * vm1 + cb1[1] * o0 + cb1[2] * o1 + cb1[3] * vp2 + cb1[4] * vp3;

      om1_0 = o0; om1_1 = o1;   // f0[k-2] still holds OLD value when read above
      f0[k] = n0; f1[k] = n1;
    }
    // NOTE on k>=2 path: f0[k-2] was overwritten with the NEW value two k-steps
    // ago — so hm2a must come from a saved old value instead. Fixed via om2:
    // (handled by om registers below — see corrected loop ordering)
  }

  // store: only waves whose 8 cols lie in the interior window [32s, 32s+32)
  const int rel = c0 - 32 * s;
  if (rel >= 0 && rel < 32) {
    float* outp = x_out + n * XL * XL;
    float4* o0p = (float4*)(outp + r0 * XL + c0);
    float4* o1p = (float4*)(outp + r1 * XL + c0);
#pragma unroll
    for (int m = 0; m < 2; ++m) {
      o0p[m] = make_float4(f0[4 * m], f0[4 * m + 1], f0[4 * m + 2], f0[4 * m + 3]);
      o1p[m] = make_float4(f1[4 * m], f1[4 * m + 1], f1[4 * m + 2], f1[4 * m + 3]);
    }
  }
}

// ---- corrected kernel: the version above has a stale-value hazard on
// f0[k-2]/f1[k-2]; this is the authoritative kernel actually launched.
__global__ __launch_bounds__(512)
void fd_reg_kernel2(const float* __restrict__ x_in, const float* __restrict__ bands,
                    const int* __restrict__ fdp, float* __restrict__ x_out) {
  __shared__ float4 hbuf[2][8][2][64];   // 32 KB

  const int tid = threadIdx.x;
  const int z = tid & 63;
  const int w = tid >> 6;
  const int n = blockIdx.x >> 2;
  const int s = blockIdx.x & 3;
  int cs0 = 32 * s - 16; if (cs0 < 0) cs0 = 0; if (cs0 > 64) cs0 = 64;
  const int c0 = cs0 + 8 * w;
  const int r0 = 2 * z, r1 = 2 * z + 1;

  const float* img = x_in + n * XL * XL;

  float f0[8], f1[8];
  {
    const float4* a = (const float4*)(img + r0 * XL + c0);
    const float4* b = (const float4*)(img + r1 * XL + c0);
#pragma unroll
    for (int m = 0; m < 2; ++m) {
      const float4 v = a[m];
      f0[4 * m] = v.x; f0[4 * m + 1] = v.y; f0[4 * m + 2] = v.z; f0[4 * m + 3] = v.w;
      const float4 u = b[m];
      f1[4 * m] = u.x; f1[4 * m + 1] = u.y; f1[4 * m + 2] = u.z; f1[4 * m + 3] = u.w;
    }
  }

  float rbi[5], rbe0[5], rbe1[5], rbe6[5], rbe7[5], cb0[5], cb1[5];
#pragma unroll
  for (int d = 0; d < 5; ++d) {
    rbi[d]  = bands[d * XL + 64];
    rbe0[d] = bands[d * XL + c0];
    rbe1[d] = bands[d * XL + c0 + 1];
    rbe6[d] = bands[d * XL + c0 + 6];
    rbe7[d] = bands[d * XL + c0 + 7];
    cb0[d]  = bands[(5 + d) * XL + r0];
    cb1[d]  = bands[(5 + d) * XL + r1];
  }

  const int fdb = fdp[0];
  const int wl = (w > 0) ? w - 1 : 0;
  const int wr = (w < 7) ? w + 1 : 7;

  for (int t = 0; t < fdb; ++t) {
    const int b = t & 1;
    hbuf[b][w][0][z] = make_float4(f0[0], f0[1], f1[0], f1[1]);
    hbuf[b][w][1][z] = make_float4(f0[6], f0[7], f1[6], f1[7]);
    __syncthreads();
    const float4 lh = hbuf[b][wl][1][z];
    const float4 rh = hbuf[b][wr][0][z];

    float om2_0 = lh.x, om1_0 = lh.y;   // old f[k-2], f[k-1] entering k=0
    float om2_1 = lh.z, om1_1 = lh.w;
#pragma unroll
    for (int k = 0; k < 8; ++k) {
      const float o0 = f0[k], o1 = f1[k];
      const float vm2 = dpp_shr1(o0);
      const float vm1 = dpp_shr1(o1);
      const float vp2 = dpp_shl1(o0);
      const float vp3 = dpp_shl1(o1);
      const float hp1_0 = (k < 7) ? f0[k + 1] : rh.x;
      const float hp2_0 = (k < 6) ? f0[k + 2] : ((k == 6) ? rh.x : rh.y);
      const float hp1_1 = (k < 7) ? f1[k + 1] : rh.z;
      const float hp2_1 = (k < 6) ? f1[k + 2] : ((k == 6) ? rh.z : rh.w);
      float c0b, c1b, c2b, c3b, c4b;
      if (k == 0)      { c0b = rbe0[0]; c1b = rbe0[1]; c2b = rbe0[2]; c3b = rbe0[3]; c4b = rbe0[4]; }
      else if (k == 1) { c0b = rbe1[0]; c1b = rbe1[1]; c2b = rbe1[2]; c3b = rbe1[3]; c4b = rbe1[4]; }
      else if (k == 6) { c0b = rbe6[0]; c1b = rbe6[1]; c2b = rbe6[2]; c3b = rbe6[3]; c4b = rbe6[4]; }
      else if (k == 7) { c0b = rbe7[0]; c1b = rbe7[1]; c2b = rbe7[2]; c3b = rbe7[3]; c4b = rbe7[4]; }
      else             { c0b = rbi[0];  c1b = rbi[1];  c2b = rbi[2];  c3b = rbi[3];  c4b = rbi[4];  }

      const float n0 = o0
        + c0b * om2_0 + c1b * om1_0 + c2b * o0 + c3b * hp1_0 + c4b * hp2_0
        + cb0[0] * vm2 + cb0[1] * vm1 + cb0[2] * o0 + cb0[3] * o1 + cb0[4] * vp2;
      const float n1 = o1
        + c0b * om2_1 + c1b * om1_1 + c2b * o1 + c3b * hp1_1 + c4b * hp2_1
        + cb1[0] * vm1 + cb1[1] * o0 + cb1[2] * o1 + cb1[3] * vp2 + cb1[4] * vp3;

      om2_0 = om1_0; om1_0 = o0;   // keep OLD values for the next col's taps
      om2_1 = om1_1; om1_1 = o1;
      f0[k] = n0; f1[k] = n1;
    }
  }

  const int rel = c0 - 32 * s;
  if (rel >= 0 && rel < 32) {
    float* outp = x_out + n * XL * XL;
    float4* o0p = (float4*)(outp + r0 * XL + c0);
    float4* o1p = (float4*)(outp + r1 * XL + c0);
#pragma unroll
    for (int m = 0; m < 2; ++m) {
      o0p[m] = make_float4(f0[4 * m], f0[4 * m + 1], f0[4 * m + 2], f0[4 * m + 3]);
      o1p[m] = make_float4(f1[4 * m], f1[4 * m + 1], f1[4 * m + 2], f1[4 * m + 3]);
    }
  }
}

extern "C" void kernel_launch(void* const* d_in, const int* in_sizes, int n_in,
                              void* d_out, int out_size, void* d_ws, size_t ws_size,
                              hipStream_t stream) {
  const float* xInput = (const float*)d_in[0];
  const float* wX1  = (const float*)d_in[1];
  const float* wX1L = (const float*)d_in[2];
  const float* wX1R = (const float*)d_in[3];
  const float* wY1  = (const float*)d_in[4];
  const float* wY1L = (const float*)d_in[5];
  const float* wY1R = (const float*)d_in[6];
  const float* wX2  = (const float*)d_in[7];
  const float* wX2L = (const float*)d_in[8];
  const float* wX2R = (const float*)d_in[9];
  const float* wY2  = (const float*)d_in[10];
  const float* wY2L = (const float*)d_in[11];
  const float* wY2R = (const float*)d_in[12];
  const float* wfc  = (const float*)d_in[13];
  const int*   fdp  = (const int*)d_in[14];

  float* bands = (float*)d_ws;   // 2*5*128 floats = 5120 B
  float* out = (float*)d_out;

  build_bands_kernel<<<5, 256, 0, stream>>>(wX1, wX1L, wX1R, wY1, wY1L, wY1R,
                                            wX2, wX2L, wX2R, wY2, wY2L, wY2R,
                                            wfc, bands);
  fd_reg_kernel2<<<256, 512, 0, stream>>>(xInput, bands, fdp, out);
}